// Round 5
// baseline (844.134 us; speedup 1.0000x reference)
//
#include <hip/hip_runtime.h>
#include <math.h>

// LieNet round 8 = round 7 with the h_gemm swizzle bug fixed.
// (1) XCD-chunked block swizzle: bid = (phys%8)*256 + phys/8. Logical blocks
//     n, n+4, n+8 share h row-blocks (as c/b/a); chunking puts them on the
//     SAME XCD so A-staging hits the 4MB L2 instead of loaded L3/HBM.
// (2) LDS XOR swizzle on A/W tiles (8-way bank conflict -> 2-way free):
//     - global_load_lds paths: swizzle the GLOBAL source col, LDS linear
//       (rule #21), reader applies slot = quad ^ (row&3).
//     - reg-staged path (h_gemm A): load LINEAR global col, store to
//       SWIZZLED LDS slot. Round-7 bug: swizzled both sides -> they
//       cancelled, reader then un-swizzled wrong data (absmax 208).
// Schedule unchanged: 2 fused passes, 8 waves, depth-1 prefetch,
// vmcnt(0)+s_barrier per K-slice. P buffers (PSTR=264) already 2-way free.

typedef unsigned short u16;
typedef __attribute__((ext_vector_type(8))) short short8;
typedef __attribute__((ext_vector_type(4))) float floatx4;

#define DD 256
#define PSTR 264          // P-lds row stride (elems)
#define NCOL 65536        // scan columns = B*D
#define SEGS 8            // scan segments (64 s-steps each)

__device__ __forceinline__ float gelu_f(float v) {
    // tanh-form gelu; |err| vs exact erf-gelu ~3e-4, far under bf16 rounding
    float u = 0.7978845608028654f * v * (1.0f + 0.044715f * v * v);
    float e = __expf(2.0f * u);
    float t = 1.0f - 2.0f * __builtin_amdgcn_rcpf(e + 1.0f);
    return 0.5f * v * (1.0f + t);
}
__device__ __forceinline__ u16 bf_bits(float f) {
    __bf16 b = (__bf16)f;
    return __builtin_bit_cast(unsigned short, b);
}
__device__ __forceinline__ float bf2f(u16 u) {
    unsigned int x = ((unsigned int)u) << 16;
    return __builtin_bit_cast(float, x);
}

#define AS1(p) ((const __attribute__((address_space(1))) unsigned int*)(p))
#define AS3(p) ((__attribute__((address_space(3))) unsigned int*)(p))

__device__ __forceinline__ void gload(const u16* src, u16* dst) {
    __builtin_amdgcn_global_load_lds(AS1(src), AS3(dst), 16, 0, 0);
}

// ---------------- fused delta+J kernel ----------------
// Tile: 64 rows x 256 cols, 512 threads (8 waves).
// Wave split: wm = w>>2 (rows wm*32..+32), wn = w&3 (cols wn*64..+64).
// A/B frag: idx=lane&15, k=quad*8+e. C/D: col=lane&15, row=quad*4+r
// (HW-verified layout carried over unchanged).
__global__ __launch_bounds__(512, 2) void fused_kernel(
    const u16* __restrict__ h, const u16* __restrict__ Wt,  // Wt [16][256][32]
    const float* __restrict__ bias, float* __restrict__ out)
{
    __shared__ u16 Ab[2][3][64 * 32];   // [buf][slice a/b/c][64r][32k]  24 KB
    __shared__ u16 Wb[2][256 * 32];     // [buf][256n][32k]              32 KB
    __shared__ u16 Pl[3][64 * PSTR];    // P_bc, P_ca, P_ab              99 KB

    const int tid = threadIdx.x;
    const int w = tid >> 6, lane = tid & 63;
    const int quad = lane >> 4, lr = lane & 15;
    const int wm = w >> 2, wn = w & 3;
    // XCD-chunked bijective swizzle (2048 % 8 == 0): consecutive logical
    // blocks (which share h rows) land on one XCD's L2.
    const int bid = ((int)blockIdx.x & 7) * 256 + ((int)blockIdx.x >> 3);
    const long m0 = (long)bid * 64;
    const bool has_x = (m0 >= 256);
    const bool has_J = (m0 >= 512);

    // LDS XOR-swizzle slots (involution: stored slot = col4 ^ (row&3)).
    const int ssw = (((lane & 3) ^ ((lane >> 2) & 3)) * 8);  // staging src col
    const int rsw = ((quad ^ (lane & 3)) * 8);               // reader slot

    // a = h[m0-512], b = h[m0-256], c = h[m0]; clamp invalid ptrs in-bounds
    const u16* hA0 = h + (has_J ? (m0 - 512) : m0) * DD;
    const u16* hA1 = h + (has_x ? (m0 - 256) : m0) * DD;
    const u16* hA2 = h + m0 * DD;

    float bias_r[4];
    #pragma unroll
    for (int j = 0; j < 4; ++j) bias_r[j] = bias[wn * 64 + j * 16 + lr];

    floatx4 acc0[2][4], acc1[2][4], acc2[2][4], Jacc[2][4];

    auto zero3 = [&]() {
        floatx4 z = {0.f, 0.f, 0.f, 0.f};
        #pragma unroll
        for (int i = 0; i < 2; ++i)
            #pragma unroll
            for (int j = 0; j < 4; ++j) { acc0[i][j] = z; acc1[i][j] = z; acc2[i][j] = z; }
    };

    // Stage K-slice kt into buffer buf. Waves 0-3: 4 W chunks each (16 total,
    // contiguous 1KB in tiled Wt). Waves 4-7: 3 A chunks each (a,b,c 64x32
    // slices = 12 chunks). Global source col pre-swizzled (ssw); LDS linear.
    auto stage = [&](int buf, int kt, bool withA) {
        if (w < 4) {
            #pragma unroll
            for (int g = 0; g < 4; ++g) {
                const int G = w * 4 + g;
                gload(Wt + kt * 8192 + G * 512 + (lane >> 2) * 32 + ssw,
                      &Wb[buf][G * 512]);
            }
        } else if (withA) {
            const int colq = (kt & 7) * 32;
            #pragma unroll
            for (int k = 0; k < 3; ++k) {
                const int c = (w - 4) * 3 + k;
                const int s = c >> 2, g = c & 3;
                const u16* hs = (s == 0) ? hA0 : ((s == 1) ? hA1 : hA2);
                gload(hs + (g * 16 + (lane >> 2)) * DD + colq + ssw,
                      &Ab[buf][0][0] + s * 2048 + g * 512);
            }
        }
    };

    // 24 MFMAs: acc0 += A[rD]*W, acc1 += A[rP2]*W, acc2 += A[rP3]*W
    auto mma3 = [&](const u16* Abase, int rD, int rP2, int rP3,
                    const u16* Wbase, bool zD) {
        short8 bfr[4];
        #pragma unroll
        for (int j = 0; j < 4; ++j)
            bfr[j] = *(const short8*)(Wbase + (wn * 64 + j * 16 + lr) * 32 + rsw);
        #pragma unroll
        for (int i = 0; i < 2; ++i) {
            const int ro = (wm * 32 + i * 16 + lr) * 32 + rsw;
            short8 a0 = *(const short8*)(Abase + rD * 2048 + ro);
            short8 a1 = *(const short8*)(Abase + rP2 * 2048 + ro);
            short8 a2 = *(const short8*)(Abase + rP3 * 2048 + ro);
            if (zD) a0 = (short8){0, 0, 0, 0, 0, 0, 0, 0};
            #pragma unroll
            for (int j = 0; j < 4; ++j) {
                acc0[i][j] = __builtin_amdgcn_mfma_f32_16x16x32_bf16(a0, bfr[j], acc0[i][j], 0, 0, 0);
                acc1[i][j] = __builtin_amdgcn_mfma_f32_16x16x32_bf16(a1, bfr[j], acc1[i][j], 0, 0, 0);
                acc2[i][j] = __builtin_amdgcn_mfma_f32_16x16x32_bf16(a2, bfr[j], acc2[i][j], 0, 0, 0);
            }
        }
    };

    // Pass-2 upper half: A operands from the three P buffers at col colp.
    // PSTR=264 already gives 2-way-free banks; no XOR here.
    auto mma3P = [&](const u16* Wbase, int colp) {
        short8 bfr[4];
        #pragma unroll
        for (int j = 0; j < 4; ++j)
            bfr[j] = *(const short8*)(Wbase + (wn * 64 + j * 16 + lr) * 32 + rsw);
        #pragma unroll
        for (int i = 0; i < 2; ++i) {
            const int ro = (wm * 32 + i * 16 + lr) * PSTR + colp + quad * 8;
            short8 a0 = *(const short8*)(&Pl[0][0] + ro);
            short8 a1 = *(const short8*)(&Pl[1][0] + ro);
            short8 a2 = *(const short8*)(&Pl[2][0] + ro);
            #pragma unroll
            for (int j = 0; j < 4; ++j) {
                acc0[i][j] = __builtin_amdgcn_mfma_f32_16x16x32_bf16(a0, bfr[j], acc0[i][j], 0, 0, 0);
                acc1[i][j] = __builtin_amdgcn_mfma_f32_16x16x32_bf16(a1, bfr[j], acc1[i][j], 0, 0, 0);
                acc2[i][j] = __builtin_amdgcn_mfma_f32_16x16x32_bf16(a2, bfr[j], acc2[i][j], 0, 0, 0);
            }
        }
    };

    // ---- Pass 1: D / P2(ca) / P3(ab). Role rotation at kt=8:
    // kt<8:  D<-b, P2<-c, P3<-a   (all at col kt*32)
    // kt>=8: D<-c, P2<-a, P3<-b   (all at col (kt-8)*32)
    zero3();
    stage(0, 0, true);
    #pragma unroll
    for (int kt = 0; kt < 16; ++kt) {
        asm volatile("s_waitcnt vmcnt(0)" ::: "memory");
        __builtin_amdgcn_s_barrier();
        if (kt < 15) stage((kt + 1) & 1, kt + 1, true);
        const bool lo = kt < 8;
        mma3(&Ab[kt & 1][0][0], lo ? 1 : 2, lo ? 2 : 0, lo ? 0 : 1,
             Wb[kt & 1], !has_x && lo);
    }

    // Prefetch pass-2 slice 0 under the epilogue (buf 0 free after kt=15).
    if (has_J) stage(0, 0, true);

    // Pass-1 epilogue: P_bc/P_ca/P_ab to LDS, Jacc = gelu(D)+x.
    #pragma unroll
    for (int j = 0; j < 4; ++j) {
        const int n = wn * 64 + j * 16 + lr;
        #pragma unroll
        for (int i = 0; i < 2; ++i) {
            const int rl = wm * 32 + i * 16 + quad * 4;
            #pragma unroll
            for (int r = 0; r < 4; ++r) {
                float gD = gelu_f(acc0[i][j][r] + bias_r[j]);
                float xv = has_x ? bf2f(h[(m0 - 256 + rl + r) * DD + n]) : 0.0f;
                Jacc[i][j][r] = gD + xv;
                if (has_J) {
                    Pl[0][(rl + r) * PSTR + n] = bf_bits(gD);
                    Pl[1][(rl + r) * PSTR + n] = bf_bits(gelu_f(acc1[i][j][r] + bias_r[j]));
                    Pl[2][(rl + r) * PSTR + n] = bf_bits(gelu_f(acc2[i][j][r] + bias_r[j]));
                }
            }
        }
    }
    __syncthreads();   // P visible (and pass-2 slice-0 loads long complete)

    // ---- Pass 2: J1/J2/J3. kt<8: A from a/b/c; kt>=8: A from P buffers.
    if (has_J) {
        zero3();
        #pragma unroll
        for (int kt = 0; kt < 16; ++kt) {
            asm volatile("s_waitcnt vmcnt(0)" ::: "memory");
            __builtin_amdgcn_s_barrier();
            if (kt < 15) stage((kt + 1) & 1, kt + 1, (kt + 1) < 8);
            if (kt < 8) mma3(&Ab[kt & 1][0][0], 0, 1, 2, Wb[kt & 1], false);
            else        mma3P(Wb[kt & 1], (kt - 8) * 32);
        }
    }

    // Output: delta (+J) per row, fp32.
    #pragma unroll
    for (int j = 0; j < 4; ++j) {
        const int n = wn * 64 + j * 16 + lr;
        #pragma unroll
        for (int i = 0; i < 2; ++i) {
            const int rl = wm * 32 + i * 16 + quad * 4;
            #pragma unroll
            for (int r = 0; r < 4; ++r) {
                float v = Jacc[i][j][r];
                if (has_J)
                    v += gelu_f(acc0[i][j][r] + bias_r[j])
                       + gelu_f(acc1[i][j][r] + bias_r[j])
                       + gelu_f(acc2[i][j][r] + bias_r[j]);
                out[(m0 + rl + r) * DD + n] = v;
            }
        }
    }
}

// ---------------- h projection (fp32 src -> bf16 h), XOR-swizzled LDS ------
__global__ __launch_bounds__(256) void h_gemm(
    const float* __restrict__ src, const u16* __restrict__ Wm,  // Wm [256][256]
    const float* __restrict__ bias, u16* __restrict__ hout)
{
    __shared__ u16 Alds[128 * 32];
    __shared__ u16 Blds[128 * 32];

    const int tid = threadIdx.x;
    const int bm = blockIdx.x * 128;
    const int bn = blockIdx.y * 128;
    const int w = tid >> 6, lane = tid & 63;
    const int quad = lane >> 4, lr = lane & 15;
    const int wm = (w & 1) * 64, wn = (w >> 1) * 64;
    const int ssw = (((lane & 3) ^ ((lane >> 2) & 3)) * 8);
    const int rsw = ((quad ^ (lane & 3)) * 8);

    floatx4 acc[4][4];
    {
        floatx4 z = {0.f, 0.f, 0.f, 0.f};
        #pragma unroll
        for (int i = 0; i < 4; ++i)
            #pragma unroll
            for (int j = 0; j < 4; ++j) acc[i][j] = z;
    }

    for (int k0 = 0; k0 < 256; k0 += 32) {
        __syncthreads();
        #pragma unroll
        for (int i = 0; i < 2; ++i) {          // A: reg-staged fp32 -> bf16
            const int row = w * 32 + i * 16 + (lane >> 2);
            // load LINEAR global col; store to SWIZZLED LDS slot (rule #21,
            // reg-staged variant). Round-7 bug was swizzling both sides.
            const long g = (long)(bm + row) * DD + k0 + (lane & 3) * 8;
            floatx4 f0 = *(const floatx4*)(src + g);
            floatx4 f1 = *(const floatx4*)(src + g + 4);
            short8 v;
            #pragma unroll
            for (int e = 0; e < 4; ++e) {
                v[e]     = (short)bf_bits(f0[e]);
                v[e + 4] = (short)bf_bits(f1[e]);
            }
            *(short8*)&Alds[row * 32 + ssw] = v;
        }
        #pragma unroll
        for (int i = 0; i < 2; ++i) {          // W tile: gload, source-swizzled
            const int row = w * 32 + i * 16 + (lane >> 2);
            const long g = (long)(bn + row) * DD + k0 + ssw;
            __builtin_amdgcn_global_load_lds(
                AS1(Wm + g), AS3(Blds + (w * 32 + i * 16) * 32), 16, 0, 0);
        }
        __syncthreads();

        short8 af[4], bfr[4];
        #pragma unroll
        for (int i = 0; i < 4; ++i)
            af[i] = *(const short8*)&Alds[(wm + i * 16 + lr) * 32 + rsw];
        #pragma unroll
        for (int j = 0; j < 4; ++j)
            bfr[j] = *(const short8*)&Blds[(wn + j * 16 + lr) * 32 + rsw];
        #pragma unroll
        for (int i = 0; i < 4; ++i)
            #pragma unroll
            for (int j = 0; j < 4; ++j)
                acc[i][j] = __builtin_amdgcn_mfma_f32_16x16x32_bf16(af[i], bfr[j], acc[i][j], 0, 0, 0);
    }

    #pragma unroll
    for (int j = 0; j < 4; ++j) {
        const int n = bn + wn + j * 16 + lr;
        const float bv = bias[n];
        #pragma unroll
        for (int i = 0; i < 4; ++i) {
            const int m = bm + wm + i * 16 + quad * 4;
            #pragma unroll
            for (int r = 0; r < 4; ++r)
                hout[(long)(m + r) * DD + n] = bf_bits(gelu_f(acc[i][j][r] + bv));
        }
    }
}

// fp32 -> bf16: map_w normal (65536), bl_w K-tiled Wt[k/32][n][k%32] (131072)
__global__ __launch_bounds__(256) void conv_w(const float* __restrict__ mw,
                                              const float* __restrict__ bw,
                                              u16* __restrict__ outw)
{
    const int i = blockIdx.x * 256 + threadIdx.x;
    if (i < 65536) {
        outw[i] = bf_bits(mw[i]);
    } else {
        const int j = i - 65536;               // bl_w [256][512] row-major
        const int n = j >> 9, k = j & 511;
        outw[65536 + (k >> 5) * 8192 + n * 32 + (k & 31)] = bf_bits(bw[j]);
    }
}

// ---------------- hierarchical cumsum over s (512 rows x 65536 cols) --------
__global__ __launch_bounds__(256) void seg_sum_kernel(
    const float* __restrict__ out, float* __restrict__ sums)
{
    const int idx = blockIdx.x * 256 + threadIdx.x;      // 0..524287
    const int seg = idx >> 16, col = idx & (NCOL - 1);
    const float* p = out + (long)seg * 64 * NCOL + col;
    float a = 0.f;
    #pragma unroll 8
    for (int s = 0; s < 64; ++s) a += p[(long)s * NCOL];
    sums[seg * NCOL + col] = a;
}

__global__ __launch_bounds__(256) void seg_offset_kernel(float* __restrict__ sums)
{
    const int col = blockIdx.x * 256 + threadIdx.x;
    float a = 0.f;
    #pragma unroll
    for (int g = 0; g < SEGS; ++g) {
        float v = sums[g * NCOL + col];
        sums[g * NCOL + col] = a;
        a += v;
    }
}

__global__ __launch_bounds__(256) void seg_apply_kernel(
    float* __restrict__ out, const float* __restrict__ sums)
{
    const int idx = blockIdx.x * 256 + threadIdx.x;
    const int seg = idx >> 16, col = idx & (NCOL - 1);
    float a = sums[seg * NCOL + col];
    float* p = out + (long)seg * 64 * NCOL + col;
    #pragma unroll 8
    for (int s = 0; s < 64; ++s) {
        a += p[(long)s * NCOL];
        p[(long)s * NCOL] = a;
    }
}

extern "C" void kernel_launch(void* const* d_in, const int* in_sizes, int n_in,
                              void* d_out, int out_size, void* d_ws, size_t ws_size,
                              hipStream_t stream)
{
    const float* src   = (const float*)d_in[0];
    const float* map_w = (const float*)d_in[1];
    const float* map_b = (const float*)d_in[2];
    const float* bl_w  = (const float*)d_in[3];
    const float* bl_b  = (const float*)d_in[4];
    float* out = (float*)d_out;

    const int SB = 512 * 256;                 // 131072 rows

    u16* h_bf = (u16*)d_ws;                   // 64 MB
    u16* wbuf = h_bf + (long)SB * DD;         // 196608 u16
    u16* wmap = wbuf;
    u16* wbl  = wbuf + 65536;                 // tiled Wt
    float* sums = (float*)(wbuf + 196608);    // 2 MB scan scratch

    const dim3 blk(256);

    conv_w<<<dim3(768), blk, 0, stream>>>(map_w, bl_w, wbuf);
    h_gemm<<<dim3(SB / 128, 2), blk, 0, stream>>>(src, wmap, map_b, h_bf);
    fused_kernel<<<dim3(SB / 64), dim3(512), 0, stream>>>(h_bf, wbl, bl_b, out);
    seg_sum_kernel<<<dim3(SEGS * NCOL / 256), blk, 0, stream>>>(out, sums);
    seg_offset_kernel<<<dim3(NCOL / 256), blk, 0, stream>>>(sums);
    seg_apply_kernel<<<dim3(SEGS * NCOL / 256), blk, 0, stream>>>(out, sums);
}

// Round 6
// 742.175 us; speedup vs baseline: 1.1374x; 1.1374x over previous
//
#include <hip/hip_runtime.h>
#include <math.h>

// LieNet round 9: TLP experiment. Same fused algorithm (2 passes, role
// rotation, P in LDS) but 1024 threads / 16 waves = 4 waves/SIMD (was 2).
// Rationale: three structurally different schedules (r1/r3/r5) all plateau
// at ~110 cyc/MFMA/SIMD (5.7x the 19.4-cyc pipe rate) with MfmaUtil ~15.5%;
// counters rule out HBM (6.5%), L2 locality (FETCH dropped 80->54MB, dur
// flat) and bank conflicts (~6%). Common factor: 2 waves/SIMD of barrier-
// coherent waves - every stall is amortized over only 2-deep TLP. This
// round doubles wave depth with a leaner per-wave tile (16x64, acc 48 regs).
// Keep: XCD-chunked block swizzle, XOR LDS swizzle, depth-1 prefetch,
// vmcnt(0)+s_barrier per K-slice, W pre-tiled [k/32][n][k%32].

typedef unsigned short u16;
typedef __attribute__((ext_vector_type(8))) short short8;
typedef __attribute__((ext_vector_type(4))) float floatx4;

#define DD 256
#define PSTR 264          // P-lds row stride (elems)
#define NCOL 65536        // scan columns = B*D
#define SEGS 8            // scan segments (64 s-steps each)

__device__ __forceinline__ float gelu_f(float v) {
    // tanh-form gelu; |err| vs exact erf-gelu ~3e-4, far under bf16 rounding
    float u = 0.7978845608028654f * v * (1.0f + 0.044715f * v * v);
    float e = __expf(2.0f * u);
    float t = 1.0f - 2.0f * __builtin_amdgcn_rcpf(e + 1.0f);
    return 0.5f * v * (1.0f + t);
}
__device__ __forceinline__ u16 bf_bits(float f) {
    __bf16 b = (__bf16)f;
    return __builtin_bit_cast(unsigned short, b);
}
__device__ __forceinline__ float bf2f(u16 u) {
    unsigned int x = ((unsigned int)u) << 16;
    return __builtin_bit_cast(float, x);
}

#define AS1(p) ((const __attribute__((address_space(1))) unsigned int*)(p))
#define AS3(p) ((__attribute__((address_space(3))) unsigned int*)(p))

__device__ __forceinline__ void gload(const u16* src, u16* dst) {
    __builtin_amdgcn_global_load_lds(AS1(src), AS3(dst), 16, 0, 0);
}

// ---------------- fused delta+J kernel ----------------
// Tile: 64 rows x 256 cols, 1024 threads (16 waves).
// Wave split: wm = w>>2 (rows wm*16..+16), wn = w&3 (cols wn*64..+64).
// A/B frag: idx=lane&15, k=quad*8+e. C/D: col=lane&15, row=quad*4+r
// (HW-verified layout carried over unchanged).
__global__ __launch_bounds__(1024, 4) void fused_kernel(
    const u16* __restrict__ h, const u16* __restrict__ Wt,  // Wt [16][256][32]
    const float* __restrict__ bias, float* __restrict__ out)
{
    __shared__ u16 Ab[2][3][64 * 32];   // [buf][slice a/b/c][64r][32k]  24 KB
    __shared__ u16 Wb[2][256 * 32];     // [buf][256n][32k]              32 KB
    __shared__ u16 Pl[3][64 * PSTR];    // P_bc, P_ca, P_ab              99 KB

    const int tid = threadIdx.x;
    const int w = tid >> 6, lane = tid & 63;
    const int quad = lane >> 4, lr = lane & 15;
    const int wm = w >> 2, wn = w & 3;
    // XCD-chunked bijective swizzle (2048 % 8 == 0): consecutive logical
    // blocks (which share h rows) land on one XCD's L2.
    const int bid = ((int)blockIdx.x & 7) * 256 + ((int)blockIdx.x >> 3);
    const long m0 = (long)bid * 64;
    const bool has_x = (m0 >= 256);
    const bool has_J = (m0 >= 512);

    // LDS XOR-swizzle slots (involution: stored slot = col4 ^ (row&3)).
    const int ssw = (((lane & 3) ^ ((lane >> 2) & 3)) * 8);  // staging src col
    const int rsw = ((quad ^ (lane & 3)) * 8);               // reader slot

    // a = h[m0-512], b = h[m0-256], c = h[m0]; clamp invalid ptrs in-bounds
    const u16* hA0 = h + (has_J ? (m0 - 512) : m0) * DD;
    const u16* hA1 = h + (has_x ? (m0 - 256) : m0) * DD;
    const u16* hA2 = h + m0 * DD;

    float bias_r[4];
    #pragma unroll
    for (int j = 0; j < 4; ++j) bias_r[j] = bias[wn * 64 + j * 16 + lr];

    floatx4 acc0[4], acc1[4], acc2[4], Jacc[4];

    auto zero3 = [&]() {
        floatx4 z = {0.f, 0.f, 0.f, 0.f};
        #pragma unroll
        for (int j = 0; j < 4; ++j) { acc0[j] = z; acc1[j] = z; acc2[j] = z; }
    };

    // Stage K-slice kt into buffer buf. Each wave: its own 1KB W chunk
    // (G = w, contiguous in tiled Wt); waves 0-11 additionally one A chunk
    // (slice s = w>>2 of a/b/c, 16-row group g = w&3). vmcnt(0) per iter
    // makes per-wave load counts irrelevant.
    auto stage = [&](int buf, int kt, bool withA) {
        gload(Wt + kt * 8192 + w * 512 + (lane >> 2) * 32 + ssw,
              &Wb[buf][w * 512]);
        if (withA && w < 12) {
            const int colq = (kt & 7) * 32;
            const int s = w >> 2, g = w & 3;
            const u16* hs = (s == 0) ? hA0 : ((s == 1) ? hA1 : hA2);
            gload(hs + (g * 16 + (lane >> 2)) * DD + colq + ssw,
                  &Ab[buf][0][0] + s * 2048 + g * 512);
        }
    };

    // 12 MFMAs: acc0 += A[rD]*W, acc1 += A[rP2]*W, acc2 += A[rP3]*W
    auto mma3 = [&](const u16* Abase, int rD, int rP2, int rP3,
                    const u16* Wbase, bool zD) {
        short8 bfr[4];
        #pragma unroll
        for (int j = 0; j < 4; ++j)
            bfr[j] = *(const short8*)(Wbase + (wn * 64 + j * 16 + lr) * 32 + rsw);
        const int ro = (wm * 16 + lr) * 32 + rsw;
        short8 a0 = *(const short8*)(Abase + rD * 2048 + ro);
        short8 a1 = *(const short8*)(Abase + rP2 * 2048 + ro);
        short8 a2 = *(const short8*)(Abase + rP3 * 2048 + ro);
        if (zD) a0 = (short8){0, 0, 0, 0, 0, 0, 0, 0};
        #pragma unroll
        for (int j = 0; j < 4; ++j) {
            acc0[j] = __builtin_amdgcn_mfma_f32_16x16x32_bf16(a0, bfr[j], acc0[j], 0, 0, 0);
            acc1[j] = __builtin_amdgcn_mfma_f32_16x16x32_bf16(a1, bfr[j], acc1[j], 0, 0, 0);
            acc2[j] = __builtin_amdgcn_mfma_f32_16x16x32_bf16(a2, bfr[j], acc2[j], 0, 0, 0);
        }
    };

    // Pass-2 upper half: A operands from the three P buffers at col colp.
    auto mma3P = [&](const u16* Wbase, int colp) {
        short8 bfr[4];
        #pragma unroll
        for (int j = 0; j < 4; ++j)
            bfr[j] = *(const short8*)(Wbase + (wn * 64 + j * 16 + lr) * 32 + rsw);
        const int ro = (wm * 16 + lr) * PSTR + colp + quad * 8;
        short8 a0 = *(const short8*)(&Pl[0][0] + ro);
        short8 a1 = *(const short8*)(&Pl[1][0] + ro);
        short8 a2 = *(const short8*)(&Pl[2][0] + ro);
        #pragma unroll
        for (int j = 0; j < 4; ++j) {
            acc0[j] = __builtin_amdgcn_mfma_f32_16x16x32_bf16(a0, bfr[j], acc0[j], 0, 0, 0);
            acc1[j] = __builtin_amdgcn_mfma_f32_16x16x32_bf16(a1, bfr[j], acc1[j], 0, 0, 0);
            acc2[j] = __builtin_amdgcn_mfma_f32_16x16x32_bf16(a2, bfr[j], acc2[j], 0, 0, 0);
        }
    };

    // ---- Pass 1: D / P2(ca) / P3(ab). Role rotation at kt=8:
    // kt<8:  D<-b, P2<-c, P3<-a   (all at col kt*32)
    // kt>=8: D<-c, P2<-a, P3<-b   (all at col (kt-8)*32)
    zero3();
    stage(0, 0, true);
    #pragma unroll
    for (int kt = 0; kt < 16; ++kt) {
        asm volatile("s_waitcnt vmcnt(0)" ::: "memory");
        __builtin_amdgcn_s_barrier();
        if (kt < 15) stage((kt + 1) & 1, kt + 1, true);
        const bool lo = kt < 8;
        mma3(&Ab[kt & 1][0][0], lo ? 1 : 2, lo ? 2 : 0, lo ? 0 : 1,
             Wb[kt & 1], !has_x && lo);
    }

    // Prefetch pass-2 slice 0 under the epilogue (buf 0 free after kt=15).
    if (has_J) stage(0, 0, true);

    // Pass-1 epilogue: P_bc/P_ca/P_ab to LDS, Jacc = gelu(D)+x.
    #pragma unroll
    for (int j = 0; j < 4; ++j) {
        const int n = wn * 64 + j * 16 + lr;
        const int rl = wm * 16 + quad * 4;
        #pragma unroll
        for (int r = 0; r < 4; ++r) {
            float gD = gelu_f(acc0[j][r] + bias_r[j]);
            float xv = has_x ? bf2f(h[(m0 - 256 + rl + r) * DD + n]) : 0.0f;
            Jacc[j][r] = gD + xv;
            if (has_J) {
                Pl[0][(rl + r) * PSTR + n] = bf_bits(gD);
                Pl[1][(rl + r) * PSTR + n] = bf_bits(gelu_f(acc1[j][r] + bias_r[j]));
                Pl[2][(rl + r) * PSTR + n] = bf_bits(gelu_f(acc2[j][r] + bias_r[j]));
            }
        }
    }
    __syncthreads();   // P visible (and pass-2 slice-0 loads long complete)

    // ---- Pass 2: J1/J2/J3. kt<8: A from a/b/c; kt>=8: A from P buffers.
    if (has_J) {
        zero3();
        #pragma unroll
        for (int kt = 0; kt < 16; ++kt) {
            asm volatile("s_waitcnt vmcnt(0)" ::: "memory");
            __builtin_amdgcn_s_barrier();
            if (kt < 15) stage((kt + 1) & 1, kt + 1, (kt + 1) < 8);
            if (kt < 8) mma3(&Ab[kt & 1][0][0], 0, 1, 2, Wb[kt & 1], false);
            else        mma3P(Wb[kt & 1], (kt - 8) * 32);
        }
    }

    // Output: delta (+J) per row, fp32.
    #pragma unroll
    for (int j = 0; j < 4; ++j) {
        const int n = wn * 64 + j * 16 + lr;
        const int rl = wm * 16 + quad * 4;
        #pragma unroll
        for (int r = 0; r < 4; ++r) {
            float v = Jacc[j][r];
            if (has_J)
                v += gelu_f(acc0[j][r] + bias_r[j])
                   + gelu_f(acc1[j][r] + bias_r[j])
                   + gelu_f(acc2[j][r] + bias_r[j]);
            out[(m0 + rl + r) * DD + n] = v;
        }
    }
}

// ---------------- h projection (fp32 src -> bf16 h), XOR-swizzled LDS ------
__global__ __launch_bounds__(256) void h_gemm(
    const float* __restrict__ src, const u16* __restrict__ Wm,  // Wm [256][256]
    const float* __restrict__ bias, u16* __restrict__ hout)
{
    __shared__ u16 Alds[128 * 32];
    __shared__ u16 Blds[128 * 32];

    const int tid = threadIdx.x;
    const int bm = blockIdx.x * 128;
    const int bn = blockIdx.y * 128;
    const int w = tid >> 6, lane = tid & 63;
    const int quad = lane >> 4, lr = lane & 15;
    const int wm = (w & 1) * 64, wn = (w >> 1) * 64;
    const int ssw = (((lane & 3) ^ ((lane >> 2) & 3)) * 8);
    const int rsw = ((quad ^ (lane & 3)) * 8);

    floatx4 acc[4][4];
    {
        floatx4 z = {0.f, 0.f, 0.f, 0.f};
        #pragma unroll
        for (int i = 0; i < 4; ++i)
            #pragma unroll
            for (int j = 0; j < 4; ++j) acc[i][j] = z;
    }

    for (int k0 = 0; k0 < 256; k0 += 32) {
        __syncthreads();
        #pragma unroll
        for (int i = 0; i < 2; ++i) {          // A: reg-staged fp32 -> bf16
            const int row = w * 32 + i * 16 + (lane >> 2);
            // linear global col; SWIZZLED LDS slot (rule #21 reg-staged form)
            const long g = (long)(bm + row) * DD + k0 + (lane & 3) * 8;
            floatx4 f0 = *(const floatx4*)(src + g);
            floatx4 f1 = *(const floatx4*)(src + g + 4);
            short8 v;
            #pragma unroll
            for (int e = 0; e < 4; ++e) {
                v[e]     = (short)bf_bits(f0[e]);
                v[e + 4] = (short)bf_bits(f1[e]);
            }
            *(short8*)&Alds[row * 32 + ssw] = v;
        }
        #pragma unroll
        for (int i = 0; i < 2; ++i) {          // W tile: gload, source-swizzled
            const int row = w * 32 + i * 16 + (lane >> 2);
            const long g = (long)(bn + row) * DD + k0 + ssw;
            __builtin_amdgcn_global_load_lds(
                AS1(Wm + g), AS3(Blds + (w * 32 + i * 16) * 32), 16, 0, 0);
        }
        __syncthreads();

        short8 af[4], bfr[4];
        #pragma unroll
        for (int i = 0; i < 4; ++i)
            af[i] = *(const short8*)&Alds[(wm + i * 16 + lr) * 32 + rsw];
        #pragma unroll
        for (int j = 0; j < 4; ++j)
            bfr[j] = *(const short8*)&Blds[(wn + j * 16 + lr) * 32 + rsw];
        #pragma unroll
        for (int i = 0; i < 4; ++i)
            #pragma unroll
            for (int j = 0; j < 4; ++j)
                acc[i][j] = __builtin_amdgcn_mfma_f32_16x16x32_bf16(af[i], bfr[j], acc[i][j], 0, 0, 0);
    }

    #pragma unroll
    for (int j = 0; j < 4; ++j) {
        const int n = bn + wn + j * 16 + lr;
        const float bv = bias[n];
        #pragma unroll
        for (int i = 0; i < 4; ++i) {
            const int m = bm + wm + i * 16 + quad * 4;
            #pragma unroll
            for (int r = 0; r < 4; ++r)
                hout[(long)(m + r) * DD + n] = bf_bits(gelu_f(acc[i][j][r] + bv));
        }
    }
}

// fp32 -> bf16: map_w normal (65536), bl_w K-tiled Wt[k/32][n][k%32] (131072)
__global__ __launch_bounds__(256) void conv_w(const float* __restrict__ mw,
                                              const float* __restrict__ bw,
                                              u16* __restrict__ outw)
{
    const int i = blockIdx.x * 256 + threadIdx.x;
    if (i < 65536) {
        outw[i] = bf_bits(mw[i]);
    } else {
        const int j = i - 65536;               // bl_w [256][512] row-major
        const int n = j >> 9, k = j & 511;
        outw[65536 + (k >> 5) * 8192 + n * 32 + (k & 31)] = bf_bits(bw[j]);
    }
}

// ---------------- hierarchical cumsum over s (512 rows x 65536 cols) --------
__global__ __launch_bounds__(256) void seg_sum_kernel(
    const float* __restrict__ out, float* __restrict__ sums)
{
    const int idx = blockIdx.x * 256 + threadIdx.x;      // 0..524287
    const int seg = idx >> 16, col = idx & (NCOL - 1);
    const float* p = out + (long)seg * 64 * NCOL + col;
    float a = 0.f;
    #pragma unroll 8
    for (int s = 0; s < 64; ++s) a += p[(long)s * NCOL];
    sums[seg * NCOL + col] = a;
}

__global__ __launch_bounds__(256) void seg_offset_kernel(float* __restrict__ sums)
{
    const int col = blockIdx.x * 256 + threadIdx.x;
    float a = 0.f;
    #pragma unroll
    for (int g = 0; g < SEGS; ++g) {
        float v = sums[g * NCOL + col];
        sums[g * NCOL + col] = a;
        a += v;
    }
}

__global__ __launch_bounds__(256) void seg_apply_kernel(
    float* __restrict__ out, const float* __restrict__ sums)
{
    const int idx = blockIdx.x * 256 + threadIdx.x;
    const int seg = idx >> 16, col = idx & (NCOL - 1);
    float a = sums[seg * NCOL + col];
    float* p = out + (long)seg * 64 * NCOL + col;
    #pragma unroll 8
    for (int s = 0; s < 64; ++s) {
        a += p[(long)s * NCOL];
        p[(long)s * NCOL] = a;
    }
}

extern "C" void kernel_launch(void* const* d_in, const int* in_sizes, int n_in,
                              void* d_out, int out_size, void* d_ws, size_t ws_size,
                              hipStream_t stream)
{
    const float* src   = (const float*)d_in[0];
    const float* map_w = (const float*)d_in[1];
    const float* map_b = (const float*)d_in[2];
    const float* bl_w  = (const float*)d_in[3];
    const float* bl_b  = (const float*)d_in[4];
    float* out = (float*)d_out;

    const int SB = 512 * 256;                 // 131072 rows

    u16* h_bf = (u16*)d_ws;                   // 64 MB
    u16* wbuf = h_bf + (long)SB * DD;         // 196608 u16
    u16* wmap = wbuf;
    u16* wbl  = wbuf + 65536;                 // tiled Wt
    float* sums = (float*)(wbuf + 196608);    // 2 MB scan scratch

    const dim3 blk(256);

    conv_w<<<dim3(768), blk, 0, stream>>>(map_w, bl_w, wbuf);
    h_gemm<<<dim3(SB / 128, 2), blk, 0, stream>>>(src, wmap, map_b, h_bf);
    fused_kernel<<<dim3(SB / 64), dim3(1024), 0, stream>>>(h_bf, wbl, bl_b, out);
    seg_sum_kernel<<<dim3(SEGS * NCOL / 256), blk, 0, stream>>>(out, sums);
    seg_offset_kernel<<<dim3(NCOL / 256), blk, 0, stream>>>(sums);
    seg_apply_kernel<<<dim3(SEGS * NCOL / 256), blk, 0, stream>>>(out, sums);
}